// Round 2
// baseline (218.841 us; speedup 1.0000x reference)
//
#include <hip/hip_runtime.h>
#include <hip/hip_bf16.h>

#define B_ 32
#define S_ 4096
#define H_ 512

typedef short bf16x8 __attribute__((ext_vector_type(8)));
typedef unsigned short u16x8 __attribute__((ext_vector_type(8)));
typedef float f32x4 __attribute__((ext_vector_type(4)));

__device__ inline unsigned short f2bf(float x) {
    unsigned u = __float_as_uint(x);
    return (unsigned short)((u + 0x7fffu + ((u >> 16) & 1u)) >> 16);
}

__device__ inline float fast_tanh(float x) {
    float e = __expf(2.f * x);
    return 1.f - 2.f / (e + 1.f);
}

// async global->LDS, 16B per lane; lds base must be wave-uniform (HW adds lane*16)
__device__ __forceinline__ void stage16(const void* g, void* lds_base, int lane) {
#if defined(__has_builtin) && __has_builtin(__builtin_amdgcn_global_load_lds)
    __builtin_amdgcn_global_load_lds(
        (const __attribute__((address_space(1))) unsigned char*)g,
        (__attribute__((address_space(3))) unsigned char*)lds_base, 16, 0, 0);
#else
    ((uint4*)lds_base)[lane] = *(const uint4*)g;
#endif
}

// ---------------------------------------------------------------------------
// Kernel 1: transpose+convert Ua[h][d] (f32) -> ua_t[d][h] (bf16, row-major)
// grid (16,16), block (32,8)
// ---------------------------------------------------------------------------
__global__ void k_prep_ua(const float* __restrict__ Ua,
                          unsigned short* __restrict__ ua_t) {
    __shared__ float tile[32][33];
    int h0 = blockIdx.x * 32, d0 = blockIdx.y * 32;
    int tx = threadIdx.x, ty = threadIdx.y;
#pragma unroll
    for (int j = 0; j < 4; ++j)
        tile[ty + j * 8][tx] = Ua[(size_t)(h0 + ty + j * 8) * H_ + d0 + tx];
    __syncthreads();
#pragma unroll
    for (int j = 0; j < 4; ++j) {
        int dl = ty + j * 8;
        ua_t[(size_t)(d0 + dl) * H_ + h0 + tx] = f2bf(tile[tx][dl]);
    }
}

// ---------------------------------------------------------------------------
// Kernel 2: q_proj[b][d] = sum_h query[b][h] * Wa[h][d]   (fp32, tiny)
// ---------------------------------------------------------------------------
__global__ __launch_bounds__(512) void k_qproj(const float* __restrict__ query,
                                               const float* __restrict__ Wa,
                                               float* __restrict__ qproj) {
    __shared__ float q[H_];
    int b = blockIdx.x, d = threadIdx.x;
    q[d] = query[(size_t)b * H_ + d];
    __syncthreads();
    float acc = 0.f;
    for (int h = 0; h < H_; ++h)
        acc = fmaf(q[h], Wa[(size_t)h * H_ + d], acc);
    qproj[(size_t)b * H_ + d] = acc;
}

// ---------------------------------------------------------------------------
// Kernel 3: partial scores. Block tile 128(M) x 128(N), BK=64, 512 thr / 8 waves,
// wave owns 64x32 (4mf x 2nf frags of 16x16x32 bf16 MFMA).
// A (keys f32) reg-staged with pipelined prefetch + f2bf; B (ua_t bf16) via
// global_load_lds, XOR-swizzle ((row&7)<<4) pre-applied to global src addr.
// Emits partial score (sum over this block's 128 d-cols) -> part_sc[nb][b][s].
// grid (32, 4, 32) = (m-tile, n-tile, batch)
// ---------------------------------------------------------------------------
__global__ __launch_bounds__(512, 4) void k_scores(
    const float* __restrict__ keys, const unsigned short* __restrict__ ua_t,
    const float* __restrict__ qproj, const float* __restrict__ Va,
    float* __restrict__ part_sc) {
    __shared__ __align__(16) unsigned char As[16384];  // [128 rows][128 B] swizzled
    __shared__ __align__(16) unsigned char Bs[16384];  // [128 rows][128 B] swizzled
    __shared__ float smp[4][128];

    int tid = threadIdx.x;
    int wave = tid >> 6, lane = tid & 63;
    int lq = lane & 15, lh = lane >> 4;
    int wm = wave >> 2;      // 0..1: row half (64 rows)
    int wnn = wave & 3;      // 0..3: col quarter (32 cols)
    int b = blockIdx.z, nb = blockIdx.y, m0 = blockIdx.x * 128;

    const float* keysb = keys + (size_t)b * S_ * H_;

    // --- A staging map: thread -> row r=tid>>2 (0..127), quarter qtr=tid&3 (16 f32)
    int r = tid >> 2, qtr = tid & 3;
    const float* aptr = keysb + (size_t)(m0 + r) * H_ + qtr * 16;
    unsigned aswz = (unsigned)((r & 7) << 4);
    unsigned abase = (unsigned)(r * 128);

    // --- B staging map: 2 issues x 8 waves x 64 lanes x 16B = 16 KB
    int rb0 = wave * 8 + (lane >> 3);        // issue 0 row
    int rb1 = 64 + rb0;                      // issue 1 row
    unsigned cb = (unsigned)((lane & 7) * 16);
    const unsigned char* uab = (const unsigned char*)ua_t;
    const unsigned char* bsrc0 = uab + ((size_t)(nb * 128 + rb0)) * 1024 + (cb ^ ((rb0 & 7) << 4));
    const unsigned char* bsrc1 = uab + ((size_t)(nb * 128 + rb1)) * 1024 + (cb ^ ((rb1 & 7) << 4));
    unsigned char* ldsB0 = Bs + wave * 1024;
    unsigned char* ldsB1 = Bs + 8192 + wave * 1024;

    f32x4 acc[4][2];
#pragma unroll
    for (int i = 0; i < 4; ++i)
#pragma unroll
        for (int j = 0; j < 2; ++j) acc[i][j] = (f32x4){0.f, 0.f, 0.f, 0.f};

    unsigned swzR = (unsigned)((lq & 7) << 4);

    float4 ar[2][4];
#pragma unroll
    for (int j = 0; j < 4; ++j) ar[0][j] = *(const float4*)(aptr + j * 4);

#pragma unroll
    for (int t = 0; t < 8; ++t) {
        const int cur = t & 1, nxt = cur ^ 1;
        __syncthreads();   // previous iteration's LDS reads complete
        // prefetch next A tile (overlaps with staging + compute below)
        if (t < 7) {
#pragma unroll
            for (int j = 0; j < 4; ++j)
                ar[nxt][j] = *(const float4*)(aptr + (t + 1) * 64 + j * 4);
        }
        // B tile: async global->LDS (swizzle folded into global address)
        stage16(bsrc0 + t * 128, ldsB0, lane);
        stage16(bsrc1 + t * 128, ldsB1, lane);
        // A tile: convert 16 f32 -> 16 bf16, 2x ds_write_b128 (swizzled)
#pragma unroll
        for (int j16 = 0; j16 < 2; ++j16) {
            float4 x = ar[cur][2 * j16], y = ar[cur][2 * j16 + 1];
            u16x8 v;
            v[0] = f2bf(x.x); v[1] = f2bf(x.y); v[2] = f2bf(x.z); v[3] = f2bf(x.w);
            v[4] = f2bf(y.x); v[5] = f2bf(y.y); v[6] = f2bf(y.z); v[7] = f2bf(y.w);
            *(u16x8*)(As + abase + ((unsigned)(qtr * 32 + j16 * 16) ^ aswz)) = v;
        }
        __syncthreads();   // drains vmcnt (B async + A prefetch) + lgkm (A writes)

#pragma unroll
        for (int ks = 0; ks < 2; ++ks) {
            bf16x8 af[4], bv[2];
            unsigned koff = (unsigned)(ks * 64 + lh * 16) ^ swzR;
#pragma unroll
            for (int mf = 0; mf < 4; ++mf)
                af[mf] = *(const bf16x8*)(As + (unsigned)((wm * 64 + mf * 16 + lq) * 128) + koff);
#pragma unroll
            for (int nf = 0; nf < 2; ++nf)
                bv[nf] = *(const bf16x8*)(Bs + (unsigned)((wnn * 32 + nf * 16 + lq) * 128) + koff);
#pragma unroll
            for (int mf = 0; mf < 4; ++mf)
#pragma unroll
                for (int nf = 0; nf < 2; ++nf)
                    acc[mf][nf] = __builtin_amdgcn_mfma_f32_16x16x32_bf16(
                        af[mf], bv[nf], acc[mf][nf], 0, 0, 0);
        }
    }

    // epilogue: partial score over this block's 128 d-columns
    float va_r[2], qp_r[2];
#pragma unroll
    for (int nf = 0; nf < 2; ++nf) {
        int n = nb * 128 + wnn * 32 + nf * 16 + lq;
        va_r[nf] = Va[n];
        qp_r[nf] = qproj[(size_t)b * H_ + n];
    }
#pragma unroll
    for (int mf = 0; mf < 4; ++mf) {
#pragma unroll
        for (int reg = 0; reg < 4; ++reg) {
            float p = va_r[0] * fast_tanh(qp_r[0] + acc[mf][0][reg])
                    + va_r[1] * fast_tanh(qp_r[1] + acc[mf][1][reg]);
            p += __shfl_xor(p, 1);
            p += __shfl_xor(p, 2);
            p += __shfl_xor(p, 4);
            p += __shfl_xor(p, 8);
            if (lq == 0) smp[wnn][wm * 64 + mf * 16 + lh * 4 + reg] = p;
        }
    }
    __syncthreads();
    if (tid < 128) {
        float s = smp[0][tid] + smp[1][tid] + smp[2][tid] + smp[3][tid];
        part_sc[((size_t)nb * B_ + b) * S_ + m0 + tid] = s;
    }
}

// ---------------------------------------------------------------------------
// Kernel 4: merge 4 n-partials (fixed order, deterministic) + softmax -> wts
// grid (32), block (512), 8 elems/thread
// ---------------------------------------------------------------------------
__global__ __launch_bounds__(512) void k_softmax(const float* __restrict__ part_sc,
                                                 float* __restrict__ wts) {
    __shared__ float red[8];
    int b = blockIdx.x, tid = threadIdx.x;
    const float* p0 = part_sc + (size_t)b * S_;
    const float* p1 = p0 + (size_t)B_ * S_;
    const float* p2 = p1 + (size_t)B_ * S_;
    const float* p3 = p2 + (size_t)B_ * S_;
    float v[8];
    float m = -1e30f;
#pragma unroll
    for (int i = 0; i < 8; ++i) {
        int s = tid + i * 512;
        v[i] = ((p0[s] + p1[s]) + (p2[s] + p3[s]));
        m = fmaxf(m, v[i]);
    }
#pragma unroll
    for (int o = 1; o < 64; o <<= 1) m = fmaxf(m, __shfl_xor(m, o));
    if ((tid & 63) == 0) red[tid >> 6] = m;
    __syncthreads();
    m = red[0];
#pragma unroll
    for (int w = 1; w < 8; ++w) m = fmaxf(m, red[w]);
    float sum = 0.f;
#pragma unroll
    for (int i = 0; i < 8; ++i) {
        v[i] = __expf(v[i] - m);
        sum += v[i];
    }
#pragma unroll
    for (int o = 1; o < 64; o <<= 1) sum += __shfl_xor(sum, o);
    __syncthreads();
    if ((tid & 63) == 0) red[tid >> 6] = sum;
    __syncthreads();
    float tot = 0.f;
#pragma unroll
    for (int w = 0; w < 8; ++w) tot += red[w];
    float inv = 1.f / tot;
#pragma unroll
    for (int i = 0; i < 8; ++i) wts[(size_t)b * S_ + tid + i * 512] = v[i] * inv;
}

// ---------------------------------------------------------------------------
// Kernel 5: partial context over 128-row chunks. grid (32,32), block (512)
// ---------------------------------------------------------------------------
__global__ __launch_bounds__(512) void k_ctx_part(const float* __restrict__ keys,
                                                  const float* __restrict__ wts,
                                                  float* __restrict__ part) {
    int c = blockIdx.x, b = blockIdx.y, h = threadIdx.x;
    const float* wrow = wts + (size_t)b * S_ + c * 128;
    const float* kbase = keys + ((size_t)b * S_ + c * 128) * H_ + h;
    float acc = 0.f;
#pragma unroll 8
    for (int s = 0; s < 128; ++s)
        acc = fmaf(wrow[s], kbase[(size_t)s * H_], acc);
    part[((size_t)c * B_ + b) * H_ + h] = acc;
}

// ---------------------------------------------------------------------------
// Kernel 6: reduce partials -> context. grid (32), block (512)
// ---------------------------------------------------------------------------
__global__ __launch_bounds__(512) void k_ctx_reduce(const float* __restrict__ part,
                                                    float* __restrict__ ctx) {
    int b = blockIdx.x, h = threadIdx.x;
    float s = 0.f;
#pragma unroll
    for (int c = 0; c < 32; ++c) s += part[((size_t)c * B_ + b) * H_ + h];
    ctx[(size_t)b * H_ + h] = s;
}

// ---------------------------------------------------------------------------
extern "C" void kernel_launch(void* const* d_in, const int* in_sizes, int n_in,
                              void* d_out, int out_size, void* d_ws, size_t ws_size,
                              hipStream_t stream) {
    const float* query = (const float*)d_in[0];
    const float* keys  = (const float*)d_in[1];
    const float* Wa    = (const float*)d_in[2];
    const float* Ua    = (const float*)d_in[3];
    const float* Va    = (const float*)d_in[4];

    float* out = (float*)d_out;
    float* ctx = out;             // [32,512]
    float* wts = out + B_ * H_;   // [32,4096]

    char* ws = (char*)d_ws;
    unsigned short* ua_t = (unsigned short*)ws;                     // 512 KB
    float* qproj   = (float*)(ws + 524288);                         // 64 KB
    float* part_sc = (float*)(ws + 524288 + 65536);                 // 2 MB
    float* part_cx = (float*)(ws + 524288 + 65536 + 2097152);       // 2 MB

    k_prep_ua<<<dim3(16, 16), dim3(32, 8), 0, stream>>>(Ua, ua_t);
    k_qproj<<<dim3(32), dim3(512), 0, stream>>>(query, Wa, qproj);
    k_scores<<<dim3(32, 4, 32), dim3(512), 0, stream>>>(keys, ua_t, qproj, Va, part_sc);
    k_softmax<<<dim3(32), dim3(512), 0, stream>>>(part_sc, wts);
    k_ctx_part<<<dim3(32, 32), dim3(512), 0, stream>>>(keys, wts, part_cx);
    k_ctx_reduce<<<dim3(32), dim3(512), 0, stream>>>(part_cx, ctx);
}

// Round 3
// 215.856 us; speedup vs baseline: 1.0138x; 1.0138x over previous
//
#include <hip/hip_runtime.h>
#include <hip/hip_bf16.h>

#define B_ 32
#define S_ 4096
#define H_ 512

typedef short bf16x8 __attribute__((ext_vector_type(8)));
typedef unsigned short u16x8 __attribute__((ext_vector_type(8)));
typedef float f32x4 __attribute__((ext_vector_type(4)));

__device__ inline unsigned short f2bf(float x) {
    unsigned u = __float_as_uint(x);
    return (unsigned short)((u + 0x7fffu + ((u >> 16) & 1u)) >> 16);
}

__device__ inline float fast_tanh(float x) {
    float e = __expf(2.f * x);
    return 1.f - 2.f / (e + 1.f);
}

// async global->LDS, 16B per lane; lds base must be wave-uniform (HW adds lane*16)
__device__ __forceinline__ void stage16(const void* g, void* lds_base) {
    __builtin_amdgcn_global_load_lds(
        (const __attribute__((address_space(1))) unsigned char*)g,
        (__attribute__((address_space(3))) unsigned char*)lds_base, 16, 0, 0);
}

// ---------------------------------------------------------------------------
// Kernel 1: transpose+convert Ua[h][d] (f32) -> ua_t[d][h] (bf16, row-major)
// grid (16,16), block (32,8)
// ---------------------------------------------------------------------------
__global__ void k_prep_ua(const float* __restrict__ Ua,
                          unsigned short* __restrict__ ua_t) {
    __shared__ float tile[32][33];
    int h0 = blockIdx.x * 32, d0 = blockIdx.y * 32;
    int tx = threadIdx.x, ty = threadIdx.y;
#pragma unroll
    for (int j = 0; j < 4; ++j)
        tile[ty + j * 8][tx] = Ua[(size_t)(h0 + ty + j * 8) * H_ + d0 + tx];
    __syncthreads();
#pragma unroll
    for (int j = 0; j < 4; ++j) {
        int dl = ty + j * 8;
        ua_t[(size_t)(d0 + dl) * H_ + h0 + tx] = f2bf(tile[tx][dl]);
    }
}

// ---------------------------------------------------------------------------
// Kernel 2: q_proj[b][d] = sum_h query[b][h] * Wa[h][d]   (fp32, tiny)
// ---------------------------------------------------------------------------
__global__ __launch_bounds__(512) void k_qproj(const float* __restrict__ query,
                                               const float* __restrict__ Wa,
                                               float* __restrict__ qproj) {
    __shared__ float q[H_];
    int b = blockIdx.x, d = threadIdx.x;
    q[d] = query[(size_t)b * H_ + d];
    __syncthreads();
    float acc = 0.f;
    for (int h = 0; h < H_; ++h)
        acc = fmaf(q[h], Wa[(size_t)h * H_ + d], acc);
    qproj[(size_t)b * H_ + d] = acc;
}

// ---------------------------------------------------------------------------
// Kernel 3: partial scores. Tile 128(M) x 128(N), BK=64, 512 thr / 8 waves.
// Double-buffered LDS; per iteration: STAGE(next) -> compute(cur) ->
// write-A(next) -> ONE barrier, so next-tile loads fly across the compute
// phase (T3-minimum schedule). XCD-swizzled grid, nb fastest (keys L2 reuse).
// flat grid 4096 = (b:32) x (m:32) x (nb:4)
// ---------------------------------------------------------------------------
__global__ __launch_bounds__(512, 2) void k_scores(
    const float* __restrict__ keys, const unsigned short* __restrict__ ua_t,
    const float* __restrict__ qproj, const float* __restrict__ Va,
    float* __restrict__ part_sc) {
    __shared__ __align__(16) unsigned char As[2][16384];  // [128 rows][128 B] swizzled
    __shared__ __align__(16) unsigned char Bs[2][16384];
    __shared__ float smp[4][128];

    int tid = threadIdx.x;
    int wave = tid >> 6, lane = tid & 63;
    int lq = lane & 15, lh = lane >> 4;
    int wm = wave >> 2;      // 0..1: row half (64 rows)
    int wnn = wave & 3;      // 0..3: col quarter (32 cols)

    // bijective XCD swizzle (4096 % 8 == 0): consecutive logical ids land on
    // the same XCD; nb varies fastest so the 4 n-tiles re-reading the same
    // keys rows share one L2.
    int logical = (blockIdx.x & 7) * 512 + (blockIdx.x >> 3);
    int b  = logical >> 7;
    int m0 = ((logical >> 2) & 31) * 128;
    int nb = logical & 3;

    const float* keysb = keys + (size_t)b * S_ * H_;

    // --- A staging map: thread -> row r=tid>>2 (0..127), quarter qtr=tid&3 (16 f32)
    int r = tid >> 2, qtr = tid & 3;
    const float* aptr = keysb + (size_t)(m0 + r) * H_ + qtr * 16;
    unsigned aswz  = (unsigned)((r & 7) << 4);
    unsigned abase = (unsigned)(r * 128);

    // --- B staging map: 2 issues x 8 waves x 64 lanes x 16B = 16 KB
    int rb0 = wave * 8 + (lane >> 3);
    int rb1 = 64 + rb0;
    unsigned cb = (unsigned)((lane & 7) * 16);
    const unsigned char* uab = (const unsigned char*)ua_t;
    const unsigned char* bsrc0 = uab + ((size_t)(nb * 128 + rb0)) * 1024 + (cb ^ ((rb0 & 7) << 4));
    const unsigned char* bsrc1 = uab + ((size_t)(nb * 128 + rb1)) * 1024 + (cb ^ ((rb1 & 7) << 4));

    f32x4 acc[4][2];
#pragma unroll
    for (int i = 0; i < 4; ++i)
#pragma unroll
        for (int j = 0; j < 2; ++j) acc[i][j] = (f32x4){0.f, 0.f, 0.f, 0.f};

    unsigned swzR = (unsigned)((lq & 7) << 4);

    float4 arg[4];

    // ---- prologue: stage tile 0 into buffer 0
    stage16(bsrc0, &Bs[0][wave * 1024]);
    stage16(bsrc1, &Bs[0][8192 + wave * 1024]);
#pragma unroll
    for (int j = 0; j < 4; ++j) arg[j] = *(const float4*)(aptr + j * 4);
#pragma unroll
    for (int j16 = 0; j16 < 2; ++j16) {
        float4 x = arg[2 * j16], y = arg[2 * j16 + 1];
        u16x8 v;
        v[0] = f2bf(x.x); v[1] = f2bf(x.y); v[2] = f2bf(x.z); v[3] = f2bf(x.w);
        v[4] = f2bf(y.x); v[5] = f2bf(y.y); v[6] = f2bf(y.z); v[7] = f2bf(y.w);
        *(u16x8*)(&As[0][0] + abase + ((unsigned)(qtr * 32 + j16 * 16) ^ aswz)) = v;
    }
    __syncthreads();

#pragma unroll
    for (int t = 0; t < 8; ++t) {
        const int cur = t & 1, nxt = cur ^ 1;

        // 1) issue next-tile loads (fly across the compute phase below)
        if (t < 7) {
            stage16(bsrc0 + (t + 1) * 128, &Bs[nxt][wave * 1024]);
            stage16(bsrc1 + (t + 1) * 128, &Bs[nxt][8192 + wave * 1024]);
#pragma unroll
            for (int j = 0; j < 4; ++j)
                arg[j] = *(const float4*)(aptr + (t + 1) * 64 + j * 4);
        }

        // 2) compute current buffer
#pragma unroll
        for (int ks = 0; ks < 2; ++ks) {
            bf16x8 af[4], bv[2];
            unsigned koff = (unsigned)(ks * 64 + lh * 16) ^ swzR;
#pragma unroll
            for (int mf = 0; mf < 4; ++mf)
                af[mf] = *(const bf16x8*)(&As[cur][0] + (unsigned)((wm * 64 + mf * 16 + lq) * 128) + koff);
#pragma unroll
            for (int nf = 0; nf < 2; ++nf)
                bv[nf] = *(const bf16x8*)(&Bs[cur][0] + (unsigned)((wnn * 32 + nf * 16 + lq) * 128) + koff);
#pragma unroll
            for (int mf = 0; mf < 4; ++mf)
#pragma unroll
                for (int nf = 0; nf < 2; ++nf)
                    acc[mf][nf] = __builtin_amdgcn_mfma_f32_16x16x32_bf16(
                        af[mf], bv[nf], acc[mf][nf], 0, 0, 0);
        }

        // 3) convert+write next A tile (waits only on the A reg loads)
        if (t < 7) {
#pragma unroll
            for (int j16 = 0; j16 < 2; ++j16) {
                float4 x = arg[2 * j16], y = arg[2 * j16 + 1];
                u16x8 v;
                v[0] = f2bf(x.x); v[1] = f2bf(x.y); v[2] = f2bf(x.z); v[3] = f2bf(x.w);
                v[4] = f2bf(y.x); v[5] = f2bf(y.y); v[6] = f2bf(y.z); v[7] = f2bf(y.w);
                *(u16x8*)(&As[nxt][0] + abase + ((unsigned)(qtr * 32 + j16 * 16) ^ aswz)) = v;
            }
        }

        // 4) single barrier: drains vmcnt (B stage16) + lgkm (A writes)
        __syncthreads();
    }

    // epilogue: partial score over this block's 128 d-columns
    float va_r[2], qp_r[2];
#pragma unroll
    for (int nf = 0; nf < 2; ++nf) {
        int n = nb * 128 + wnn * 32 + nf * 16 + lq;
        va_r[nf] = Va[n];
        qp_r[nf] = qproj[(size_t)b * H_ + n];
    }
#pragma unroll
    for (int mf = 0; mf < 4; ++mf) {
#pragma unroll
        for (int reg = 0; reg < 4; ++reg) {
            float p = va_r[0] * fast_tanh(qp_r[0] + acc[mf][0][reg])
                    + va_r[1] * fast_tanh(qp_r[1] + acc[mf][1][reg]);
            p += __shfl_xor(p, 1);
            p += __shfl_xor(p, 2);
            p += __shfl_xor(p, 4);
            p += __shfl_xor(p, 8);
            if (lq == 0) smp[wnn][wm * 64 + mf * 16 + lh * 4 + reg] = p;
        }
    }
    __syncthreads();
    if (tid < 128) {
        float s = smp[0][tid] + smp[1][tid] + smp[2][tid] + smp[3][tid];
        part_sc[((size_t)nb * B_ + b) * S_ + m0 + tid] = s;
    }
}

// ---------------------------------------------------------------------------
// Kernel 4: merge 4 n-partials (fixed order, deterministic) + softmax -> wts
// grid (32), block (512), 8 elems/thread
// ---------------------------------------------------------------------------
__global__ __launch_bounds__(512) void k_softmax(const float* __restrict__ part_sc,
                                                 float* __restrict__ wts) {
    __shared__ float red[8];
    int b = blockIdx.x, tid = threadIdx.x;
    const float* p0 = part_sc + (size_t)b * S_;
    const float* p1 = p0 + (size_t)B_ * S_;
    const float* p2 = p1 + (size_t)B_ * S_;
    const float* p3 = p2 + (size_t)B_ * S_;
    float v[8];
    float m = -1e30f;
#pragma unroll
    for (int i = 0; i < 8; ++i) {
        int s = tid + i * 512;
        v[i] = ((p0[s] + p1[s]) + (p2[s] + p3[s]));
        m = fmaxf(m, v[i]);
    }
#pragma unroll
    for (int o = 1; o < 64; o <<= 1) m = fmaxf(m, __shfl_xor(m, o));
    if ((tid & 63) == 0) red[tid >> 6] = m;
    __syncthreads();
    m = red[0];
#pragma unroll
    for (int w = 1; w < 8; ++w) m = fmaxf(m, red[w]);
    float sum = 0.f;
#pragma unroll
    for (int i = 0; i < 8; ++i) {
        v[i] = __expf(v[i] - m);
        sum += v[i];
    }
#pragma unroll
    for (int o = 1; o < 64; o <<= 1) sum += __shfl_xor(sum, o);
    __syncthreads();
    if ((tid & 63) == 0) red[tid >> 6] = sum;
    __syncthreads();
    float tot = 0.f;
#pragma unroll
    for (int w = 0; w < 8; ++w) tot += red[w];
    float inv = 1.f / tot;
#pragma unroll
    for (int i = 0; i < 8; ++i) wts[(size_t)b * S_ + tid + i * 512] = v[i] * inv;
}

// ---------------------------------------------------------------------------
// Kernel 5: partial context over 128-row chunks. grid (32,32), block (512)
// ---------------------------------------------------------------------------
__global__ __launch_bounds__(512) void k_ctx_part(const float* __restrict__ keys,
                                                  const float* __restrict__ wts,
                                                  float* __restrict__ part) {
    int c = blockIdx.x, b = blockIdx.y, h = threadIdx.x;
    const float* wrow = wts + (size_t)b * S_ + c * 128;
    const float* kbase = keys + ((size_t)b * S_ + c * 128) * H_ + h;
    float acc = 0.f;
#pragma unroll 8
    for (int s = 0; s < 128; ++s)
        acc = fmaf(wrow[s], kbase[(size_t)s * H_], acc);
    part[((size_t)c * B_ + b) * H_ + h] = acc;
}

// ---------------------------------------------------------------------------
// Kernel 6: reduce partials -> context. grid (32), block (512)
// ---------------------------------------------------------------------------
__global__ __launch_bounds__(512) void k_ctx_reduce(const float* __restrict__ part,
                                                    float* __restrict__ ctx) {
    int b = blockIdx.x, h = threadIdx.x;
    float s = 0.f;
#pragma unroll
    for (int c = 0; c < 32; ++c) s += part[((size_t)c * B_ + b) * H_ + h];
    ctx[(size_t)b * H_ + h] = s;
}

// ---------------------------------------------------------------------------
extern "C" void kernel_launch(void* const* d_in, const int* in_sizes, int n_in,
                              void* d_out, int out_size, void* d_ws, size_t ws_size,
                              hipStream_t stream) {
    const float* query = (const float*)d_in[0];
    const float* keys  = (const float*)d_in[1];
    const float* Wa    = (const float*)d_in[2];
    const float* Ua    = (const float*)d_in[3];
    const float* Va    = (const float*)d_in[4];

    float* out = (float*)d_out;
    float* ctx = out;             // [32,512]
    float* wts = out + B_ * H_;   // [32,4096]

    char* ws = (char*)d_ws;
    unsigned short* ua_t = (unsigned short*)ws;                     // 512 KB
    float* qproj   = (float*)(ws + 524288);                         // 64 KB
    float* part_sc = (float*)(ws + 524288 + 65536);                 // 2 MB
    float* part_cx = (float*)(ws + 524288 + 65536 + 2097152);       // 2 MB

    k_prep_ua<<<dim3(16, 16), dim3(32, 8), 0, stream>>>(Ua, ua_t);
    k_qproj<<<dim3(32), dim3(512), 0, stream>>>(query, Wa, qproj);
    k_scores<<<dim3(4096), dim3(512), 0, stream>>>(keys, ua_t, qproj, Va, part_sc);
    k_softmax<<<dim3(32), dim3(512), 0, stream>>>(part_sc, wts);
    k_ctx_part<<<dim3(32, 32), dim3(512), 0, stream>>>(keys, wts, part_cx);
    k_ctx_reduce<<<dim3(32), dim3(512), 0, stream>>>(part_cx, ctx);
}